// Round 3
// baseline (255.566 us; speedup 1.0000x reference)
//
#include <hip/hip_runtime.h>

// YOLO-v1-style loss, exact port of the JAX reference.
// S=7, B=2, C=20, channels per cell = 30:
//   ch 0..19  : class scores
//   ch 20..24 : box0 x,y,w,h,conf
//   ch 25..29 : box1 x,y,w,h,conf
// cls part of the loss uses channels [5*B: i.e. 10..29] (reference quirk, kept).
//
// R6: coalesced REGISTER loads (m13 pattern) + ds_write staging (T14 split).
// R3 (TA-scatter-bound), R4/R5 (100% of bytes via the global_load_lds fill
// path) all pinned at ~2.6 TB/s delivered. This version uses the only
// load shape proven to hit 6.3 TB/s on this chip: plain global_load_dwordx4
// into VGPRs, issued one full compute-phase early (T14 issue-early /
// write-late), then full-rate ds_write_b128 into a single LDS buffer.
// Tile = 128 cells (15,360 B/tensor), LDS = 30,728 B -> 5 blocks/CU =
// 10 waves/CU; each block owns a contiguous chunk of tiles.

#define CH      30
#define EPSL    1e-6f
#define TPB     128
#define TILE_C  128                 // cells per tile
#define TILE_F  (TILE_C * CH)       // 3840 floats = 15,360 B per tensor
#define TILE_F4 (TILE_F / 4)        // 960 float4s per tensor
#define NLOAD   8                   // per-thread float4 loads per tensor (i=7 half-guarded)
#define GRID    1280                // 5 blocks/CU on 256 CUs

__device__ __forceinline__ float sgnf(float x) {
    return (x > 0.0f) ? 1.0f : ((x < 0.0f) ? -1.0f : 0.0f);
}

// Per-cell loss from channels 10..29 of p (pd) and a (ad).
__device__ __forceinline__ float cell_loss(const float* pd, const float* ad) {
    float lsum = 0.0f;

    // box attrs: channel 20+5b+i -> index 10+5b+i
    float pxv[2], pyv[2], pwv[2], phv[2], pcv[2];
    float axv[2], ayv[2], awv[2], ahv[2];
#pragma unroll
    for (int b = 0; b < 2; ++b) {
        pxv[b] = pd[10 + 5 * b]; pyv[b] = pd[11 + 5 * b];
        pwv[b] = pd[12 + 5 * b]; phv[b] = pd[13 + 5 * b];
        pcv[b] = pd[14 + 5 * b];
        axv[b] = ad[10 + 5 * b]; ayv[b] = ad[11 + 5 * b];
        awv[b] = ad[12 + 5 * b]; ahv[b] = ad[13 + 5 * b];
    }
    const bool obj = ad[14] > 0.0f;   // a's box-0 conf (channel 24)

    // ---- pairwise IoU, max over target boxes ----
    float miou[2];
#pragma unroll
    for (int pb = 0; pb < 2; ++pb) {
        const float p_tlx = pxv[pb] - 0.5f * pwv[pb];
        const float p_tly = pyv[pb] - 0.5f * phv[pb];
        const float p_brx = pxv[pb] + 0.5f * pwv[pb];
        const float p_bry = pyv[pb] + 0.5f * phv[pb];
        const float p_area = pwv[pb] * phv[pb];
        float best = -3.4e38f;
#pragma unroll
        for (int ab = 0; ab < 2; ++ab) {
            const float a_tlx = axv[ab] - 0.5f * awv[ab];
            const float a_tly = ayv[ab] - 0.5f * ahv[ab];
            const float a_brx = axv[ab] + 0.5f * awv[ab];
            const float a_bry = ayv[ab] + 0.5f * ahv[ab];
            float sx = fminf(p_brx, a_brx) - fmaxf(p_tlx, a_tlx);
            float sy = fminf(p_bry, a_bry) - fmaxf(p_tly, a_tly);
            sx = fmaxf(sx, 0.0f);
            sy = fmaxf(sy, 0.0f);
            const float inter = sx * sy;
            const float uni = p_area + awv[ab] * ahv[ab] - inter;
            const float iou = (uni == 0.0f) ? 0.0f : (inter / uni);  // where(zero,0)/where(zero,eps)
            best = fmaxf(best, iou);
        }
        miou[pb] = best;
    }
    // argmax over pred boxes, first-max tie-break (jnp.argmax semantics)
    const int resp = (miou[1] > miou[0]) ? 1 : 0;

    // ---- coordinate / confidence losses ----
#pragma unroll
    for (int b = 0; b < 2; ++b) {
        const bool oij = obj && (b == resp);
        if (oij) {
            const float dx = axv[b] - pxv[b];
            const float dy = ayv[b] - pyv[b];
            const float dw = sgnf(awv[b]) * sqrtf(awv[b] + EPSL) - sgnf(pwv[b]) * sqrtf(pwv[b] + EPSL);
            const float dh = sgnf(ahv[b]) * sqrtf(ahv[b] + EPSL) - sgnf(phv[b]) * sqrtf(phv[b] + EPSL);
            const float dc = 1.0f - pcv[b];  // (obj_ij^2 - obj_ij*pc)^2 with obj_ij==1
            lsum += 5.0f * (dx * dx + dy * dy + dw * dw + dh * dh) + dc * dc;
        } else {
            // noobj term: (noobj_ij*obj_ij - noobj_ij*pc)^2 = pc^2 when obj_ij==0
            lsum += 0.5f * pcv[b] * pcv[b];
        }
    }

    // ---- "class" loss over channels 10..29 (indices 0..19), gated by obj_i ----
    if (obj) {
#pragma unroll
        for (int k = 0; k < 20; ++k) {
            const float d = pd[k] - ad[k];
            lsum += d * d;
        }
    }
    return lsum;
}

__global__ __launch_bounds__(TPB) void yolo_loss_kernel(const float* __restrict__ p,
                                                        const float* __restrict__ a,
                                                        float* __restrict__ out,
                                                        long long n_cells) {
    __shared__ float buf[2 * TILE_F];   // p region then a region (30,720 B)
    __shared__ float wsum[TPB / 64];

    const int tid = threadIdx.x;
    const long long FT = n_cells / TILE_C;    // full tiles (6272 at this shape)
    const long long nb = gridDim.x;
    const long long b  = blockIdx.x;
    // contiguous chunk of tiles per block (streaming-friendly)
    const long long q = FT / nb, r = FT % nb;
    const long long start = b * q + (b < r ? b : r);
    const long long end   = start + q + (b < r ? 1 : 0);

    float lsum = 0.0f;
    float4 rp[NLOAD], ra[NLOAD];

    long long t = start;
    // ---- prologue: load + write tile 'start' ----
    if (t < end) {
        const float4* gp = (const float4*)(p + t * (long long)TILE_F);
        const float4* ga = (const float4*)(a + t * (long long)TILE_F);
#pragma unroll
        for (int i = 0; i < NLOAD; ++i) {
            const int idx = i * TPB + tid;
            if (idx < TILE_F4) { rp[i] = gp[idx]; ra[i] = ga[idx]; }
        }
#pragma unroll
        for (int i = 0; i < NLOAD; ++i) {
            const int idx = i * TPB + tid;
            if (idx < TILE_F4) {
                *(float4*)(buf + (size_t)idx * 4)          = rp[i];
                *(float4*)(buf + TILE_F + (size_t)idx * 4) = ra[i];
            }
        }
    }
    __syncthreads();

    for (; t < end; ++t) {
        const long long tn = t + 1;
        // T14 issue-early: start next tile's loads before computing current
        if (tn < end) {
            const float4* gp = (const float4*)(p + tn * (long long)TILE_F);
            const float4* ga = (const float4*)(a + tn * (long long)TILE_F);
#pragma unroll
            for (int i = 0; i < NLOAD; ++i) {
                const int idx = i * TPB + tid;
                if (idx < TILE_F4) { rp[i] = gp[idx]; ra[i] = ga[idx]; }
            }
        }

        // ---- consume current buffer ----
        {
            float pd[20], ad[20];
            const float* bp = buf + tid * CH + 10;
            const float* ba = buf + TILE_F + tid * CH + 10;
#pragma unroll
            for (int i = 0; i < 10; ++i) {
                const float2 v = *(const float2*)(bp + 2 * i);
                pd[2 * i] = v.x; pd[2 * i + 1] = v.y;
            }
#pragma unroll
            for (int i = 0; i < 10; ++i) {
                const float2 v = *(const float2*)(ba + 2 * i);
                ad[2 * i] = v.x; ad[2 * i + 1] = v.y;
            }
            lsum += cell_loss(pd, ad);
        }

        __syncthreads();   // everyone done reading buf
        // T14 write-late: loads had a full compute phase to arrive
        if (tn < end) {
#pragma unroll
            for (int i = 0; i < NLOAD; ++i) {
                const int idx = i * TPB + tid;
                if (idx < TILE_F4) {
                    *(float4*)(buf + (size_t)idx * 4)          = rp[i];
                    *(float4*)(buf + TILE_F + (size_t)idx * 4) = ra[i];
                }
            }
        }
        __syncthreads();   // buf ready for next iteration
    }

    // ---- tail cells (n_cells % TILE_C; zero at this shape) -> block 0, direct loads ----
    if (blockIdx.x == 0) {
        const long long c = FT * TILE_C + tid;
        if (c < n_cells) {
            float pd[20], ad[20];
            const float2* cp2 = (const float2*)(p + c * CH + 10);
            const float2* ca2 = (const float2*)(a + c * CH + 10);
#pragma unroll
            for (int i = 0; i < 10; ++i) {
                const float2 v = cp2[i];
                pd[2 * i] = v.x; pd[2 * i + 1] = v.y;
            }
#pragma unroll
            for (int i = 0; i < 10; ++i) {
                const float2 v = ca2[i];
                ad[2 * i] = v.x; ad[2 * i + 1] = v.y;
            }
            lsum += cell_loss(pd, ad);
        }
    }

    // ---- reduction: wave shfl -> LDS -> one atomic per block ----
    float v = lsum;
#pragma unroll
    for (int off = 32; off > 0; off >>= 1)
        v += __shfl_down(v, off, 64);
    if ((tid & 63) == 0) wsum[tid >> 6] = v;
    __syncthreads();
    if (tid == 0) {
        float t2 = 0.0f;
#pragma unroll
        for (int w = 0; w < TPB / 64; ++w) t2 += wsum[w];
        atomicAdd(out, t2);
    }
}

extern "C" void kernel_launch(void* const* d_in, const int* in_sizes, int n_in,
                              void* d_out, int out_size, void* d_ws, size_t ws_size,
                              hipStream_t stream) {
    const float* p = (const float*)d_in[0];
    const float* a = (const float*)d_in[1];
    float* out = (float*)d_out;

    const long long n_cells = (long long)in_sizes[0] / CH;   // 16384*7*7 = 802816

    // d_out is re-poisoned (0xAA) before every timed replay -> must zero it here.
    hipMemsetAsync(d_out, 0, sizeof(float), stream);
    yolo_loss_kernel<<<GRID, TPB, 0, stream>>>(p, a, out, n_cells);
}

// Round 4
// 209.523 us; speedup vs baseline: 1.2198x; 1.2198x over previous
//
#include <hip/hip_runtime.h>

// YOLO-v1-style loss, exact port of the JAX reference.
// S=7, B=2, C=20, channels per cell = 30:
//   ch 0..19  : class scores
//   ch 20..24 : box0 x,y,w,h,conf
//   ch 25..29 : box1 x,y,w,h,conf
// cls part of the loss uses channels [5*B: i.e. 10..29] (reference quirk, kept).
//
// R7 = R6 minus the scratch spill. R6's guarded float4 staging arrays were
// demoted to scratch (VGPR_Count=68, WRITE_SIZE 188 MB = per-tile 256 B/thread
// round-tripped through local memory). Fix: exact-fit UNGUARDED staging --
// 15 float2 per thread per tensor (1920 float2 = one 128-cell tile), fully
// static indices, plus __launch_bounds__(128,2) so the allocator may use up
// to 256 VGPRs instead of spilling. Structure otherwise unchanged:
// plain coalesced global_load (the m13-proven path) into registers issued one
// compute-phase early (T14), ds_write_b64 into a single 30,720-B LDS buffer
// (5 blocks/CU), contiguous tile chunk per block.

#define CH      30
#define EPSL    1e-6f
#define TPB     128
#define TILE_C  128                 // cells per tile
#define TILE_F  (TILE_C * CH)       // 3840 floats = 15,360 B per tensor
#define TILE_F2 (TILE_F / 2)        // 1920 float2 per tensor
#define NL      15                  // float2 loads per thread per tensor (exact: 15*128=1920)
#define GRID    1280                // 5 blocks/CU on 256 CUs

__device__ __forceinline__ float sgnf(float x) {
    return (x > 0.0f) ? 1.0f : ((x < 0.0f) ? -1.0f : 0.0f);
}

// Per-cell loss from channels 10..29 of p (pd) and a (ad).
__device__ __forceinline__ float cell_loss(const float* pd, const float* ad) {
    float lsum = 0.0f;

    // box attrs: channel 20+5b+i -> index 10+5b+i
    float pxv[2], pyv[2], pwv[2], phv[2], pcv[2];
    float axv[2], ayv[2], awv[2], ahv[2];
#pragma unroll
    for (int b = 0; b < 2; ++b) {
        pxv[b] = pd[10 + 5 * b]; pyv[b] = pd[11 + 5 * b];
        pwv[b] = pd[12 + 5 * b]; phv[b] = pd[13 + 5 * b];
        pcv[b] = pd[14 + 5 * b];
        axv[b] = ad[10 + 5 * b]; ayv[b] = ad[11 + 5 * b];
        awv[b] = ad[12 + 5 * b]; ahv[b] = ad[13 + 5 * b];
    }
    const bool obj = ad[14] > 0.0f;   // a's box-0 conf (channel 24)

    // ---- pairwise IoU, max over target boxes ----
    float miou[2];
#pragma unroll
    for (int pb = 0; pb < 2; ++pb) {
        const float p_tlx = pxv[pb] - 0.5f * pwv[pb];
        const float p_tly = pyv[pb] - 0.5f * phv[pb];
        const float p_brx = pxv[pb] + 0.5f * pwv[pb];
        const float p_bry = pyv[pb] + 0.5f * phv[pb];
        const float p_area = pwv[pb] * phv[pb];
        float best = -3.4e38f;
#pragma unroll
        for (int ab = 0; ab < 2; ++ab) {
            const float a_tlx = axv[ab] - 0.5f * awv[ab];
            const float a_tly = ayv[ab] - 0.5f * ahv[ab];
            const float a_brx = axv[ab] + 0.5f * awv[ab];
            const float a_bry = ayv[ab] + 0.5f * ahv[ab];
            float sx = fminf(p_brx, a_brx) - fmaxf(p_tlx, a_tlx);
            float sy = fminf(p_bry, a_bry) - fmaxf(p_tly, a_tly);
            sx = fmaxf(sx, 0.0f);
            sy = fmaxf(sy, 0.0f);
            const float inter = sx * sy;
            const float uni = p_area + awv[ab] * ahv[ab] - inter;
            const float iou = (uni == 0.0f) ? 0.0f : (inter / uni);  // where(zero,0)/where(zero,eps)
            best = fmaxf(best, iou);
        }
        miou[pb] = best;
    }
    // argmax over pred boxes, first-max tie-break (jnp.argmax semantics)
    const int resp = (miou[1] > miou[0]) ? 1 : 0;

    // ---- coordinate / confidence losses ----
#pragma unroll
    for (int b = 0; b < 2; ++b) {
        const bool oij = obj && (b == resp);
        if (oij) {
            const float dx = axv[b] - pxv[b];
            const float dy = ayv[b] - pyv[b];
            const float dw = sgnf(awv[b]) * sqrtf(awv[b] + EPSL) - sgnf(pwv[b]) * sqrtf(pwv[b] + EPSL);
            const float dh = sgnf(ahv[b]) * sqrtf(ahv[b] + EPSL) - sgnf(phv[b]) * sqrtf(phv[b] + EPSL);
            const float dc = 1.0f - pcv[b];  // (obj_ij^2 - obj_ij*pc)^2 with obj_ij==1
            lsum += 5.0f * (dx * dx + dy * dy + dw * dw + dh * dh) + dc * dc;
        } else {
            // noobj term: (noobj_ij*obj_ij - noobj_ij*pc)^2 = pc^2 when obj_ij==0
            lsum += 0.5f * pcv[b] * pcv[b];
        }
    }

    // ---- "class" loss over channels 10..29 (indices 0..19), gated by obj_i ----
    if (obj) {
#pragma unroll
        for (int k = 0; k < 20; ++k) {
            const float d = pd[k] - ad[k];
            lsum += d * d;
        }
    }
    return lsum;
}

__global__ __launch_bounds__(TPB, 2) void yolo_loss_kernel(const float* __restrict__ p,
                                                           const float* __restrict__ a,
                                                           float* __restrict__ out,
                                                           long long n_cells) {
    __shared__ float buf[2 * TILE_F];   // p region then a region (30,720 B)
    __shared__ float wsum[TPB / 64];

    const int tid = threadIdx.x;
    const long long FT = n_cells / TILE_C;    // full tiles (6272 at this shape)
    const long long nb = gridDim.x;
    const long long b  = blockIdx.x;
    // contiguous chunk of tiles per block (streaming-friendly)
    const long long q = FT / nb, r = FT % nb;
    const long long start = b * q + (b < r ? b : r);
    const long long end   = start + q + (b < r ? 1 : 0);

    float lsum = 0.0f;
    // staging registers: exact fit, no guards, static indices -> must stay VGPR
    float2 rp2[NL], ra2[NL];

    float2* const bp2 = (float2*)buf;
    float2* const ba2 = (float2*)(buf + TILE_F);

    long long t = start;
    // ---- prologue: load + write tile 'start' ----
    if (t < end) {
        const float2* gp = (const float2*)(p + t * (long long)TILE_F);
        const float2* ga = (const float2*)(a + t * (long long)TILE_F);
#pragma unroll
        for (int i = 0; i < NL; ++i) {
            rp2[i] = gp[i * TPB + tid];
            ra2[i] = ga[i * TPB + tid];
        }
#pragma unroll
        for (int i = 0; i < NL; ++i) {
            bp2[i * TPB + tid] = rp2[i];
            ba2[i * TPB + tid] = ra2[i];
        }
    }
    __syncthreads();

    for (; t < end; ++t) {
        const long long tn = t + 1;
        // T14 issue-early: start next tile's loads before computing current
        if (tn < end) {
            const float2* gp = (const float2*)(p + tn * (long long)TILE_F);
            const float2* ga = (const float2*)(a + tn * (long long)TILE_F);
#pragma unroll
            for (int i = 0; i < NL; ++i) {
                rp2[i] = gp[i * TPB + tid];
                ra2[i] = ga[i * TPB + tid];
            }
        }

        // ---- consume current buffer ----
        {
            float pd[20], ad[20];
            const float* bp = buf + tid * CH + 10;
            const float* ba = buf + TILE_F + tid * CH + 10;
#pragma unroll
            for (int i = 0; i < 10; ++i) {
                const float2 v = *(const float2*)(bp + 2 * i);
                pd[2 * i] = v.x; pd[2 * i + 1] = v.y;
            }
#pragma unroll
            for (int i = 0; i < 10; ++i) {
                const float2 v = *(const float2*)(ba + 2 * i);
                ad[2 * i] = v.x; ad[2 * i + 1] = v.y;
            }
            lsum += cell_loss(pd, ad);
        }

        __syncthreads();   // everyone done reading buf
        // T14 write-late: loads had a full compute phase to arrive
        if (tn < end) {
#pragma unroll
            for (int i = 0; i < NL; ++i) {
                bp2[i * TPB + tid] = rp2[i];
                ba2[i * TPB + tid] = ra2[i];
            }
        }
        __syncthreads();   // buf ready for next iteration
    }

    // ---- tail cells (n_cells % TILE_C; zero at this shape) -> block 0, direct loads ----
    if (blockIdx.x == 0) {
        const long long c = FT * TILE_C + tid;
        if (c < n_cells) {
            float pd[20], ad[20];
            const float2* cp2 = (const float2*)(p + c * CH + 10);
            const float2* ca2 = (const float2*)(a + c * CH + 10);
#pragma unroll
            for (int i = 0; i < 10; ++i) {
                const float2 v = cp2[i];
                pd[2 * i] = v.x; pd[2 * i + 1] = v.y;
            }
#pragma unroll
            for (int i = 0; i < 10; ++i) {
                const float2 v = ca2[i];
                ad[2 * i] = v.x; ad[2 * i + 1] = v.y;
            }
            lsum += cell_loss(pd, ad);
        }
    }

    // ---- reduction: wave shfl -> LDS -> one atomic per block ----
    float v = lsum;
#pragma unroll
    for (int off = 32; off > 0; off >>= 1)
        v += __shfl_down(v, off, 64);
    if ((tid & 63) == 0) wsum[tid >> 6] = v;
    __syncthreads();
    if (tid == 0) {
        float t2 = 0.0f;
#pragma unroll
        for (int w = 0; w < TPB / 64; ++w) t2 += wsum[w];
        atomicAdd(out, t2);
    }
}

extern "C" void kernel_launch(void* const* d_in, const int* in_sizes, int n_in,
                              void* d_out, int out_size, void* d_ws, size_t ws_size,
                              hipStream_t stream) {
    const float* p = (const float*)d_in[0];
    const float* a = (const float*)d_in[1];
    float* out = (float*)d_out;

    const long long n_cells = (long long)in_sizes[0] / CH;   // 16384*7*7 = 802816

    // d_out is re-poisoned (0xAA) before every timed replay -> must zero it here.
    hipMemsetAsync(d_out, 0, sizeof(float), stream);
    yolo_loss_kernel<<<GRID, TPB, 0, stream>>>(p, a, out, n_cells);
}

// Round 5
// 203.992 us; speedup vs baseline: 1.2528x; 1.0271x over previous
//
#include <hip/hip_runtime.h>

// YOLO-v1-style loss, exact port of the JAX reference.
// S=7, B=2, C=20, channels per cell = 30:
//   ch 0..19  : class scores
//   ch 20..24 : box0 x,y,w,h,conf
//   ch 25..29 : box1 x,y,w,h,conf
// cls part of the loss uses channels [5*B: i.e. 10..29] (reference quirk, kept).
//
// R8: R3 structure (direct loads, no LDS staging, no barriers, max occupancy)
// with the load width maxed: the live 80-B window [byte 40,120) of each cell
// is exactly 5 dwordx4 per tensor (dword alignment is sufficient for
// global_load_dwordx4 on gfx950). 10 VMEM instructions/lane vs R3's 20.
// Discriminator: R3/R4/R5/R7 all deliver ~4.3-4.5 B/cy/CU (= the read share
// of m13's copy ceiling), suggesting a per-CU outstanding-read-miss wall.
// If R3 was instead TA-request-bound, halving the request count wins ~1.5x;
// if flat, the miss wall is confirmed -> roofline.

#define CH    30
#define EPSL  1e-6f
#define TPB   256

// dword-aligned float4: lets the compiler emit global_load_dwordx4 at
// 4-byte alignment (cell base 120c+40 is 8-mod-16).
typedef float f4u __attribute__((ext_vector_type(4), aligned(4)));

__device__ __forceinline__ float sgnf(float x) {
    return (x > 0.0f) ? 1.0f : ((x < 0.0f) ? -1.0f : 0.0f);
}

__global__ __launch_bounds__(TPB) void yolo_loss_kernel(const float* __restrict__ p,
                                                        const float* __restrict__ a,
                                                        float* __restrict__ out,
                                                        long long n_cells) {
    __shared__ float wsum[TPB / 64];

    const int tid = threadIdx.x;
    const long long cell = (long long)blockIdx.x * TPB + tid;

    float lsum = 0.0f;
    if (cell < n_cells) {
        // pd[j] / ad[j] = channel (10+j) of this cell, j in [0,20)
        // = bytes [40,120) of the cell = 5 dwordx4 each.
        const f4u* cp4 = (const f4u*)((const char*)p + cell * (CH * 4) + 40);
        const f4u* ca4 = (const f4u*)((const char*)a + cell * (CH * 4) + 40);
        float pd[20], ad[20];
#pragma unroll
        for (int i = 0; i < 5; ++i) {
            const f4u v = cp4[i];
            pd[4 * i + 0] = v.x; pd[4 * i + 1] = v.y;
            pd[4 * i + 2] = v.z; pd[4 * i + 3] = v.w;
        }
#pragma unroll
        for (int i = 0; i < 5; ++i) {
            const f4u v = ca4[i];
            ad[4 * i + 0] = v.x; ad[4 * i + 1] = v.y;
            ad[4 * i + 2] = v.z; ad[4 * i + 3] = v.w;
        }

        // box attrs: channel 20+5b+i -> index 10+5b+i
        float pxv[2], pyv[2], pwv[2], phv[2], pcv[2];
        float axv[2], ayv[2], awv[2], ahv[2];
#pragma unroll
        for (int b = 0; b < 2; ++b) {
            pxv[b] = pd[10 + 5 * b]; pyv[b] = pd[11 + 5 * b];
            pwv[b] = pd[12 + 5 * b]; phv[b] = pd[13 + 5 * b];
            pcv[b] = pd[14 + 5 * b];
            axv[b] = ad[10 + 5 * b]; ayv[b] = ad[11 + 5 * b];
            awv[b] = ad[12 + 5 * b]; ahv[b] = ad[13 + 5 * b];
        }
        const bool obj = ad[14] > 0.0f;   // a's box-0 conf (channel 24)

        // ---- pairwise IoU, max over target boxes ----
        float miou[2];
#pragma unroll
        for (int pb = 0; pb < 2; ++pb) {
            const float p_tlx = pxv[pb] - 0.5f * pwv[pb];
            const float p_tly = pyv[pb] - 0.5f * phv[pb];
            const float p_brx = pxv[pb] + 0.5f * pwv[pb];
            const float p_bry = pyv[pb] + 0.5f * phv[pb];
            const float p_area = pwv[pb] * phv[pb];
            float best = -3.4e38f;
#pragma unroll
            for (int ab = 0; ab < 2; ++ab) {
                const float a_tlx = axv[ab] - 0.5f * awv[ab];
                const float a_tly = ayv[ab] - 0.5f * ahv[ab];
                const float a_brx = axv[ab] + 0.5f * awv[ab];
                const float a_bry = ayv[ab] + 0.5f * ahv[ab];
                float sx = fminf(p_brx, a_brx) - fmaxf(p_tlx, a_tlx);
                float sy = fminf(p_bry, a_bry) - fmaxf(p_tly, a_tly);
                sx = fmaxf(sx, 0.0f);
                sy = fmaxf(sy, 0.0f);
                const float inter = sx * sy;
                const float uni = p_area + awv[ab] * ahv[ab] - inter;
                const float iou = (uni == 0.0f) ? 0.0f : (inter / uni);  // where(zero,0)/where(zero,eps)
                best = fmaxf(best, iou);
            }
            miou[pb] = best;
        }
        // argmax over pred boxes, first-max tie-break (jnp.argmax semantics)
        const int resp = (miou[1] > miou[0]) ? 1 : 0;

        // ---- coordinate / confidence losses ----
#pragma unroll
        for (int b = 0; b < 2; ++b) {
            const bool oij = obj && (b == resp);
            if (oij) {
                const float dx = axv[b] - pxv[b];
                const float dy = ayv[b] - pyv[b];
                const float dw = sgnf(awv[b]) * sqrtf(awv[b] + EPSL) - sgnf(pwv[b]) * sqrtf(pwv[b] + EPSL);
                const float dh = sgnf(ahv[b]) * sqrtf(ahv[b] + EPSL) - sgnf(phv[b]) * sqrtf(phv[b] + EPSL);
                const float dc = 1.0f - pcv[b];  // (obj_ij^2 - obj_ij*pc)^2 with obj_ij==1
                lsum += 5.0f * (dx * dx + dy * dy + dw * dw + dh * dh) + dc * dc;
            } else {
                // noobj term: (noobj_ij*obj_ij - noobj_ij*pc)^2 = pc^2 when obj_ij==0
                lsum += 0.5f * pcv[b] * pcv[b];
            }
        }

        // ---- "class" loss over channels 10..29 (indices 0..19), gated by obj_i ----
        if (obj) {
#pragma unroll
            for (int k = 0; k < 20; ++k) {
                const float d = pd[k] - ad[k];
                lsum += d * d;
            }
        }
    }

    // ---- reduction: wave shfl -> LDS -> one atomic per block ----
    float v = lsum;
#pragma unroll
    for (int off = 32; off > 0; off >>= 1)
        v += __shfl_down(v, off, 64);
    if ((tid & 63) == 0) wsum[tid >> 6] = v;
    __syncthreads();
    if (tid == 0) {
        float t = 0.0f;
#pragma unroll
        for (int w = 0; w < TPB / 64; ++w) t += wsum[w];
        atomicAdd(out, t);
    }
}

extern "C" void kernel_launch(void* const* d_in, const int* in_sizes, int n_in,
                              void* d_out, int out_size, void* d_ws, size_t ws_size,
                              hipStream_t stream) {
    const float* p = (const float*)d_in[0];
    const float* a = (const float*)d_in[1];
    float* out = (float*)d_out;

    const long long n_cells = (long long)in_sizes[0] / CH;   // 16384*7*7 = 802816
    const int grid = (int)((n_cells + TPB - 1) / TPB);       // 3136, exact

    // d_out is re-poisoned (0xAA) before every timed replay -> must zero it here.
    hipMemsetAsync(d_out, 0, sizeof(float), stream);
    yolo_loss_kernel<<<grid, TPB, 0, stream>>>(p, a, out, n_cells);
}